// Round 1
// baseline (1835.224 us; speedup 1.0000x reference)
//
#include <hip/hip_runtime.h>
#include <hip/hip_fp16.h>

typedef _Float16 f16;
typedef _Float16 f16x8 __attribute__((ext_vector_type(8)));
typedef _Float16 f16x2 __attribute__((ext_vector_type(2)));
typedef float f32x4 __attribute__((ext_vector_type(4)));
typedef float f32x2 __attribute__((ext_vector_type(2)));

#define QMAXF 127.0f
#define EPSQ 1e-8f

__device__ __forceinline__ void gload_lds16(const void* g, void* l) {
  __builtin_amdgcn_global_load_lds(
      (const __attribute__((address_space(1))) unsigned int*)g,
      (__attribute__((address_space(3))) unsigned int*)l, 16, 0, 0);
}

// Group-of-128 symmetric int8 fake-quant along last dim: fp32 in -> fp16 out.
// Exact reference math in fp32 (max/127, maximum(.,eps), divide, rint, clip, q*s);
// only the final q*s -> fp16 cast loses precision (2^-12 rel).
__global__ __launch_bounds__(256)
void qdq_kernel(const float* __restrict__ in, f16* __restrict__ out, int n_groups) {
  int wid = blockIdx.x * 4 + (threadIdx.x >> 6);
  if (wid >= n_groups) return;
  int lane = threadIdx.x & 63;
  long base = (long)wid * 128 + lane * 2;
  f32x2 v = *(const f32x2*)(in + base);
  float m = fmaxf(fabsf(v.x), fabsf(v.y));
#pragma unroll
  for (int off = 32; off; off >>= 1) m = fmaxf(m, __shfl_xor(m, off));
  float s = fmaxf(m / QMAXF, EPSQ);
  float q0 = fminf(fmaxf(rintf(v.x / s), -QMAXF), QMAXF);
  float q1 = fminf(fmaxf(rintf(v.y / s), -QMAXF), QMAXF);
  f16x2 o;
  o.x = (f16)(q0 * s);
  o.y = (f16)(q1 * s);
  *(f16x2*)(out + base) = o;
}

#define BM 128
#define BN 128
#define BK 32

// Fused gate/up GEMM: Hout[m][n] = silu(A.Bg^T) * (A.Bu^T), all NT layout
// (A [M][K] row-major, B [N][K] row-major, K contiguous for both).
__global__ __launch_bounds__(256, 2)
void gemm_gateup(const f16* __restrict__ A, const f16* __restrict__ Bg,
                 const f16* __restrict__ Bu, float* __restrict__ Hout,
                 int M, int N, int K) {
  __shared__ __align__(16) f16 sA[BM * BK];
  __shared__ __align__(16) f16 sBg[BN * BK];
  __shared__ __align__(16) f16 sBu[BN * BK];
  const int tid = threadIdx.x;
  const int lane = tid & 63;
  const int wid = tid >> 6;
  const int m0 = blockIdx.y * BM;
  const int n0 = blockIdx.x * BN;
  const int wr = (wid >> 1) * 64;
  const int wc = (wid & 1) * 64;
  const int l15 = lane & 15, l4 = lane >> 4;

  f32x4 zero = {0.f, 0.f, 0.f, 0.f};
  f32x4 accg[4][4], accu[4][4];
#pragma unroll
  for (int i = 0; i < 4; i++)
#pragma unroll
    for (int j = 0; j < 4; j++) { accg[i][j] = zero; accu[i][j] = zero; }

  // staging: 512 16B-chunks per 8KB tile; thread stages chunks tid and tid+256.
  // LDS dest = wave-uniform base + lane*16 (c = j*256 + wid*64 + lane). [m104 rule]
  const int c0 = tid, c1 = tid + 256;
  const f16* gA0 = A + (long)(m0 + (c0 >> 2)) * K + (c0 & 3) * 8;
  const f16* gA1 = A + (long)(m0 + (c1 >> 2)) * K + (c1 & 3) * 8;
  const f16* gG0 = Bg + (long)(n0 + (c0 >> 2)) * K + (c0 & 3) * 8;
  const f16* gG1 = Bg + (long)(n0 + (c1 >> 2)) * K + (c1 & 3) * 8;
  const f16* gU0 = Bu + (long)(n0 + (c0 >> 2)) * K + (c0 & 3) * 8;
  const f16* gU1 = Bu + (long)(n0 + (c1 >> 2)) * K + (c1 & 3) * 8;

  for (int k0 = 0; k0 < K; k0 += BK) {
    gload_lds16(gA0 + k0, &sA[c0 * 8]);
    gload_lds16(gA1 + k0, &sA[c1 * 8]);
    gload_lds16(gG0 + k0, &sBg[c0 * 8]);
    gload_lds16(gG1 + k0, &sBg[c1 * 8]);
    gload_lds16(gU0 + k0, &sBu[c0 * 8]);
    gload_lds16(gU1 + k0, &sBu[c1 * 8]);
    __syncthreads();
    f16x8 af[4], gf[4], uf[4];
#pragma unroll
    for (int i = 0; i < 4; i++) {
      af[i] = *(const f16x8*)&sA[(wr + i * 16 + l15) * BK + l4 * 8];
      gf[i] = *(const f16x8*)&sBg[(wc + i * 16 + l15) * BK + l4 * 8];
      uf[i] = *(const f16x8*)&sBu[(wc + i * 16 + l15) * BK + l4 * 8];
    }
#pragma unroll
    for (int i = 0; i < 4; i++)
#pragma unroll
      for (int j = 0; j < 4; j++) {
        accg[i][j] = __builtin_amdgcn_mfma_f32_16x16x32_f16(af[i], gf[j], accg[i][j], 0, 0, 0);
        accu[i][j] = __builtin_amdgcn_mfma_f32_16x16x32_f16(af[i], uf[j], accu[i][j], 0, 0, 0);
      }
    __syncthreads();
  }
  // epilogue: silu(gate)*up -> fp32 hidden. C/D: col=lane&15, row=(lane>>4)*4+reg [m89]
#pragma unroll
  for (int i = 0; i < 4; i++)
#pragma unroll
    for (int j = 0; j < 4; j++)
#pragma unroll
      for (int r = 0; r < 4; r++) {
        int row = m0 + wr + i * 16 + l4 * 4 + r;
        int col = n0 + wc + j * 16 + l15;
        float g = accg[i][j][r], u = accu[i][j][r];
        float h = g / (1.f + expf(-g)) * u;
        Hout[(long)row * N + col] = h;
      }
}

// Down GEMM: C[m][n] = A.B^T, fp32 out
__global__ __launch_bounds__(256, 2)
void gemm_down(const f16* __restrict__ A, const f16* __restrict__ B,
               float* __restrict__ C, int M, int N, int K) {
  __shared__ __align__(16) f16 sA[BM * BK];
  __shared__ __align__(16) f16 sB[BN * BK];
  const int tid = threadIdx.x;
  const int lane = tid & 63;
  const int wid = tid >> 6;
  const int m0 = blockIdx.y * BM;
  const int n0 = blockIdx.x * BN;
  const int wr = (wid >> 1) * 64;
  const int wc = (wid & 1) * 64;
  const int l15 = lane & 15, l4 = lane >> 4;

  f32x4 zero = {0.f, 0.f, 0.f, 0.f};
  f32x4 acc[4][4];
#pragma unroll
  for (int i = 0; i < 4; i++)
#pragma unroll
    for (int j = 0; j < 4; j++) acc[i][j] = zero;

  const int c0 = tid, c1 = tid + 256;
  const f16* gA0 = A + (long)(m0 + (c0 >> 2)) * K + (c0 & 3) * 8;
  const f16* gA1 = A + (long)(m0 + (c1 >> 2)) * K + (c1 & 3) * 8;
  const f16* gB0 = B + (long)(n0 + (c0 >> 2)) * K + (c0 & 3) * 8;
  const f16* gB1 = B + (long)(n0 + (c1 >> 2)) * K + (c1 & 3) * 8;

  for (int k0 = 0; k0 < K; k0 += BK) {
    gload_lds16(gA0 + k0, &sA[c0 * 8]);
    gload_lds16(gA1 + k0, &sA[c1 * 8]);
    gload_lds16(gB0 + k0, &sB[c0 * 8]);
    gload_lds16(gB1 + k0, &sB[c1 * 8]);
    __syncthreads();
    f16x8 af[4], bf[4];
#pragma unroll
    for (int i = 0; i < 4; i++) {
      af[i] = *(const f16x8*)&sA[(wr + i * 16 + l15) * BK + l4 * 8];
      bf[i] = *(const f16x8*)&sB[(wc + i * 16 + l15) * BK + l4 * 8];
    }
#pragma unroll
    for (int i = 0; i < 4; i++)
#pragma unroll
      for (int j = 0; j < 4; j++)
        acc[i][j] = __builtin_amdgcn_mfma_f32_16x16x32_f16(af[i], bf[j], acc[i][j], 0, 0, 0);
    __syncthreads();
  }
#pragma unroll
  for (int i = 0; i < 4; i++)
#pragma unroll
    for (int j = 0; j < 4; j++)
#pragma unroll
      for (int r = 0; r < 4; r++) {
        int row = m0 + wr + i * 16 + l4 * 4 + r;
        int col = n0 + wc + j * 16 + l15;
        C[(long)row * N + col] = acc[i][j][r];
      }
}

extern "C" void kernel_launch(void* const* d_in, const int* in_sizes, int n_in,
                              void* d_out, int out_size, void* d_ws, size_t ws_size,
                              hipStream_t stream) {
  (void)n_in; (void)out_size;
  const float* x  = (const float*)d_in[0];
  const float* wg = (const float*)d_in[1];
  const float* wu = (const float*)d_in[2];
  const float* wd = (const float*)d_in[3];
  float* out = (float*)d_out;

  const long H = 4096;
  const long M = in_sizes[0] / H;   // 4096 (B*S)
  const long I = in_sizes[1] / H;   // 11008

  // workspace layout (bytes), with hq overlaid on the dead xq/wgq region:
  //   xq:     [0, 2*M*H)
  //   wgq:    [2*M*H, +2*I*H)
  //   wuq:    ... +2*I*H
  //   wdq:    ... +2*H*I
  //   hidden: ... +4*M*I (fp32)
  //   hq:     @0 (xq/wgq dead once gemm_gateup finished)
  char* ws = (char*)d_ws;
  size_t off = 0;
  f16* xq  = (f16*)(ws + off); off += 2L * M * H;
  f16* wgq = (f16*)(ws + off); off += 2L * I * H;
  f16* wuq = (f16*)(ws + off); off += 2L * I * H;
  f16* wdq = (f16*)(ws + off); off += 2L * H * I;
  float* hidden = (float*)(ws + off); off += 4L * M * I;
  f16* hq = (f16*)ws;  // overlay
  if (ws_size < off) return;  // insufficient workspace: fail loudly (poisoned out)

  // 1) quantize-dequantize inputs/weights -> fp16
  {
    int g;
    g = (int)(M * H / 128);
    qdq_kernel<<<dim3((g + 3) / 4), dim3(256), 0, stream>>>(x, xq, g);
    g = (int)(I * H / 128);
    qdq_kernel<<<dim3((g + 3) / 4), dim3(256), 0, stream>>>(wg, wgq, g);
    qdq_kernel<<<dim3((g + 3) / 4), dim3(256), 0, stream>>>(wu, wuq, g);
    g = (int)(H * I / 128);
    qdq_kernel<<<dim3((g + 3) / 4), dim3(256), 0, stream>>>(wd, wdq, g);
  }
  // 2) fused gate/up GEMM + SwiGLU -> fp32 hidden [M][I]
  gemm_gateup<<<dim3((unsigned)(I / BN), (unsigned)(M / BM)), 256, 0, stream>>>(
      xq, wgq, wuq, hidden, (int)M, (int)I, (int)H);
  // 3) quantize-dequantize hidden -> fp16 hq
  {
    int g = (int)(M * I / 128);
    qdq_kernel<<<dim3((g + 3) / 4), dim3(256), 0, stream>>>(hidden, hq, g);
  }
  // 4) down GEMM -> fp32 out [M][H]
  gemm_down<<<dim3((unsigned)(H / BN), (unsigned)(M / BM)), 256, 0, stream>>>(
      hq, wdq, out, (int)M, (int)H, (int)I);
}

// Round 2
// 1542.509 us; speedup vs baseline: 1.1898x; 1.1898x over previous
//
#include <hip/hip_runtime.h>
#include <math.h>

typedef _Float16 f16;
typedef _Float16 f16x8 __attribute__((ext_vector_type(8)));
typedef _Float16 f16x2 __attribute__((ext_vector_type(2)));
typedef float f32x4 __attribute__((ext_vector_type(4)));
typedef float f32x2 __attribute__((ext_vector_type(2)));

#define QMAXF 127.0f
#define EPSQ 1e-8f

__device__ __forceinline__ void gl_lds16(const f16* g, char* l) {
  __builtin_amdgcn_global_load_lds(
      (const __attribute__((address_space(1))) unsigned int*)g,
      (__attribute__((address_space(3))) unsigned int*)l, 16, 0, 0);
}

// Group-of-128 symmetric int8 fake-quant along last dim: fp32 in -> fp16 out.
// Exact reference math in fp32; only the final q*s -> fp16 cast loses precision.
__global__ __launch_bounds__(256)
void qdq_kernel(const float* __restrict__ in, f16* __restrict__ out, int n_groups) {
  int wid = blockIdx.x * 4 + (threadIdx.x >> 6);
  if (wid >= n_groups) return;
  int lane = threadIdx.x & 63;
  long base = (long)wid * 128 + lane * 2;
  f32x2 v = *(const f32x2*)(in + base);
  float m = fmaxf(fabsf(v.x), fabsf(v.y));
#pragma unroll
  for (int off = 32; off; off >>= 1) m = fmaxf(m, __shfl_xor(m, off));
  float s = fmaxf(m / QMAXF, EPSQ);
  float q0 = fminf(fmaxf(rintf(v.x / s), -QMAXF), QMAXF);
  float q1 = fminf(fmaxf(rintf(v.y / s), -QMAXF), QMAXF);
  f16x2 o;
  o.x = (f16)(q0 * s);
  o.y = (f16)(q1 * s);
  *(f16x2*)(out + base) = o;
}

// ---------------------------------------------------------------------------
// 256x256 tile, BK=64, 8 waves (2M x 4N), 512 thr, 128 KiB LDS double-buffer,
// st_16x32 XOR swizzle, 4 phases/K-tile with counted vmcnt (m201 template).
// NT layout: A [M][K], B [N][K] row-major. fp32 out.
// EPI=0: C = acc.   EPI=1: C[idx] = silu(Caux[idx]) * acc  (C may alias Caux).
// LDS map (bytes): buf b at b*65536; A-lo 0, A-hi 16384, B-lo 32768, B-hi 49152.
// Each half-tile region = [128 rows][128 bytes]; swz: byte ^= ((byte>>9)&1)<<5.
// Staging: linear LDS dest (c*16, c=tid / tid+512), inverse-swz global source.
// Half-tile re-stage safety: all A reads of a tile done by P1, B reads by P2;
// (t+2).A staged at P2/P3 (same buffer), (t+1).B staged at P0/P1 (other buffer).
// ---------------------------------------------------------------------------
template<int EPI>
__global__ __launch_bounds__(512, 1)
void gemm256(const f16* __restrict__ A, const f16* __restrict__ B,
             float* C, const float* Caux, int M, int N, int K, int NBN) {
  extern __shared__ __align__(16) char smem[];
  const int tid = threadIdx.x;
  const int lane = tid & 63;
  const int wid = tid >> 6;
  const int wm = wid >> 2, wn = wid & 3;
  const int l15 = lane & 15, l16 = lane >> 4;

  // T1: XCD-aware block swizzle (grids are %8==0)
  const int nwg = gridDim.x;
  const int wg = ((int)blockIdx.x & 7) * (nwg >> 3) + ((int)blockIdx.x >> 3);
  const long m0 = (long)(wg / NBN) * 256;
  const long n0 = (long)(wg % NBN) * 256;

  // staging chunk geometry: thread stages phys bytes [ph,ph+16) of each region;
  // logical offset = swz(phys) -> (row, colbyte) -> per-lane global source.
  const int ph0 = tid * 16;
  const int ph1 = ph0 + 8192;
  const int L0 = ph0 ^ (((ph0 >> 9) & 1) << 5);
  const int L1 = ph1 ^ (((ph1 >> 9) & 1) << 5);
  const long r0 = L0 >> 7; const int c0e = (L0 & 127) >> 1;
  const long r1 = L1 >> 7; const int c1e = (L1 & 127) >> 1;

  const f16* pAlo0 = A + (m0 + r0) * K + c0e;
  const f16* pAlo1 = A + (m0 + r1) * K + c1e;
  const f16* pAhi0 = A + (m0 + 128 + r0) * K + c0e;
  const f16* pAhi1 = A + (m0 + 128 + r1) * K + c1e;
  const f16* pBlo0 = B + (n0 + r0) * K + c0e;
  const f16* pBlo1 = B + (n0 + r1) * K + c1e;
  const f16* pBhi0 = B + (n0 + 128 + r0) * K + c0e;
  const f16* pBhi1 = B + (n0 + 128 + r1) * K + c1e;

  // fragment read bases: row = (sub)*16 + l15, colbyte = kk*64 + l16*16,
  // swz folds to XOR of bit5 by row-bit2 (= l15 bit2) on the col part.
  const int swzm = ((l15 >> 2) & 1) << 5;
  const int col0 = (l16 * 16) ^ swzm;
  const int aB = wm * 16384 + l15 * 128 + col0;                       // + i*2048 + kk*64
  const int bB = 32768 + (wn >> 1) * 16384 + (wn & 1) * 8192 + l15 * 128 + col0;  // + j*2048 + kk*64

  f32x4 acc[8][4];
#pragma unroll
  for (int i = 0; i < 8; i++)
#pragma unroll
    for (int j = 0; j < 4; j++) acc[i][j] = (f32x4){0.f, 0.f, 0.f, 0.f};

  const int kT = K / 64;

  // prologue: t0 all 4 halves -> buf0; t1 A halves -> buf1; wait t0 (leave 4)
  gl_lds16(pAlo0, smem + 0 + ph0);      gl_lds16(pAlo1, smem + 0 + ph1);
  gl_lds16(pAhi0, smem + 16384 + ph0);  gl_lds16(pAhi1, smem + 16384 + ph1);
  gl_lds16(pBlo0, smem + 32768 + ph0);  gl_lds16(pBlo1, smem + 32768 + ph1);
  gl_lds16(pBhi0, smem + 49152 + ph0);  gl_lds16(pBhi1, smem + 49152 + ph1);
  {
    const long ka = (kT > 1) ? 64 : 0;
    gl_lds16(pAlo0 + ka, smem + 65536 + 0 + ph0);
    gl_lds16(pAlo1 + ka, smem + 65536 + 0 + ph1);
    gl_lds16(pAhi0 + ka, smem + 65536 + 16384 + ph0);
    gl_lds16(pAhi1 + ka, smem + 65536 + 16384 + ph1);
  }
  asm volatile("s_waitcnt vmcnt(4)" ::: "memory");
  __builtin_amdgcn_s_barrier();

  for (int t = 0; t < kT; ++t) {
    const int cur = (t & 1) << 16;
    const int nxt = cur ^ 65536;
    const long k1 = (long)((t + 1 < kT) ? t + 1 : kT - 1) * 64;
    const long k2 = (long)((t + 2 < kT) ? t + 2 : kT - 1) * 64;
    f16x8 af[8][2], bf[2][2];

    // ---- P0: ds_read A i0-3 (8) + B j0-1 (4); stage (t+1).Blo -> nxt
#pragma unroll
    for (int i = 0; i < 4; i++)
#pragma unroll
      for (int kk = 0; kk < 2; kk++)
        af[i][kk] = *(const f16x8*)(smem + cur + aB + i * 2048 + kk * 64);
#pragma unroll
    for (int jj = 0; jj < 2; jj++)
#pragma unroll
      for (int kk = 0; kk < 2; kk++)
        bf[jj][kk] = *(const f16x8*)(smem + cur + bB + jj * 2048 + kk * 64);
    gl_lds16(pBlo0 + k1, smem + nxt + 32768 + ph0);
    gl_lds16(pBlo1 + k1, smem + nxt + 32768 + ph1);
    __builtin_amdgcn_s_barrier();
    __builtin_amdgcn_s_setprio(1);
#pragma unroll
    for (int i = 0; i < 4; i++)
#pragma unroll
      for (int jj = 0; jj < 2; jj++)
#pragma unroll
        for (int kk = 0; kk < 2; kk++)
          acc[i][jj] = __builtin_amdgcn_mfma_f32_16x16x32_f16(af[i][kk], bf[jj][kk], acc[i][jj], 0, 0, 0);
    __builtin_amdgcn_s_setprio(0);
    __builtin_amdgcn_s_barrier();

    // ---- P1: ds_read A i4-7 (8); stage (t+1).Bhi -> nxt
#pragma unroll
    for (int i = 4; i < 8; i++)
#pragma unroll
      for (int kk = 0; kk < 2; kk++)
        af[i][kk] = *(const f16x8*)(smem + cur + aB + i * 2048 + kk * 64);
    gl_lds16(pBhi0 + k1, smem + nxt + 49152 + ph0);
    gl_lds16(pBhi1 + k1, smem + nxt + 49152 + ph1);
    __builtin_amdgcn_s_barrier();
    __builtin_amdgcn_s_setprio(1);
#pragma unroll
    for (int i = 4; i < 8; i++)
#pragma unroll
      for (int jj = 0; jj < 2; jj++)
#pragma unroll
        for (int kk = 0; kk < 2; kk++)
          acc[i][jj] = __builtin_amdgcn_mfma_f32_16x16x32_f16(af[i][kk], bf[jj][kk], acc[i][jj], 0, 0, 0);
    __builtin_amdgcn_s_setprio(0);
    __builtin_amdgcn_s_barrier();

    // ---- P2: ds_read B j2-3 (4); stage (t+2).Alo -> cur (A reads done @P1)
#pragma unroll
    for (int jj = 0; jj < 2; jj++)
#pragma unroll
      for (int kk = 0; kk < 2; kk++)
        bf[jj][kk] = *(const f16x8*)(smem + cur + bB + (2 + jj) * 2048 + kk * 64);
    gl_lds16(pAlo0 + k2, smem + cur + 0 + ph0);
    gl_lds16(pAlo1 + k2, smem + cur + 0 + ph1);
    __builtin_amdgcn_s_barrier();
    __builtin_amdgcn_s_setprio(1);
#pragma unroll
    for (int i = 0; i < 4; i++)
#pragma unroll
      for (int jj = 0; jj < 2; jj++)
#pragma unroll
        for (int kk = 0; kk < 2; kk++)
          acc[i][2 + jj] = __builtin_amdgcn_mfma_f32_16x16x32_f16(af[i][kk], bf[jj][kk], acc[i][2 + jj], 0, 0, 0);
    __builtin_amdgcn_s_setprio(0);
    __builtin_amdgcn_s_barrier();

    // ---- P3: stage (t+2).Ahi -> cur; MFMA i4-7 x j2-3; counted vmcnt
    gl_lds16(pAhi0 + k2, smem + cur + 16384 + ph0);
    gl_lds16(pAhi1 + k2, smem + cur + 16384 + ph1);
    __builtin_amdgcn_s_barrier();
    __builtin_amdgcn_s_setprio(1);
#pragma unroll
    for (int i = 4; i < 8; i++)
#pragma unroll
      for (int jj = 0; jj < 2; jj++)
#pragma unroll
        for (int kk = 0; kk < 2; kk++)
          acc[i][2 + jj] = __builtin_amdgcn_mfma_f32_16x16x32_f16(af[i][kk], bf[jj][kk], acc[i][2 + jj], 0, 0, 0);
    __builtin_amdgcn_s_setprio(0);
    // leave (t+2).Alo/Ahi (4 loads) in flight; everything older (incl. t+1) drained
    asm volatile("s_waitcnt vmcnt(4)" ::: "memory");
    __builtin_amdgcn_s_barrier();
  }

  // epilogue: C/D map col=lane&15, row=(lane>>4)*4+reg
#pragma unroll
  for (int i = 0; i < 8; i++)
#pragma unroll
    for (int j = 0; j < 4; j++)
#pragma unroll
      for (int r = 0; r < 4; r++) {
        long row = m0 + wm * 128 + i * 16 + l16 * 4 + r;
        long col = n0 + wn * 64 + j * 16 + l15;
        long idx = row * N + col;
        if (EPI == 0) {
          C[idx] = acc[i][j][r];
        } else {
          float g = Caux[idx];
          C[idx] = g / (1.f + expf(-g)) * acc[i][j][r];
        }
      }
}

extern "C" void kernel_launch(void* const* d_in, const int* in_sizes, int n_in,
                              void* d_out, int out_size, void* d_ws, size_t ws_size,
                              hipStream_t stream) {
  (void)n_in; (void)out_size;
  const float* x  = (const float*)d_in[0];
  const float* wg = (const float*)d_in[1];
  const float* wu = (const float*)d_in[2];
  const float* wd = (const float*)d_in[3];
  float* out = (float*)d_out;

  const long H = 4096;
  const long M = in_sizes[0] / H;   // 4096 (B*S)
  const long I = in_sizes[1] / H;   // 11008

  // workspace: xq | wgq | wuq | wdq | gate(fp32, becomes hidden in-place)
  // hq overlays the dead xq/wgq region after the up-GEMM.
  char* ws = (char*)d_ws;
  size_t off = 0;
  f16* xq  = (f16*)(ws + off); off += 2L * M * H;
  f16* wgq = (f16*)(ws + off); off += 2L * I * H;
  f16* wuq = (f16*)(ws + off); off += 2L * I * H;
  f16* wdq = (f16*)(ws + off); off += 2L * H * I;
  float* gate = (float*)(ws + off); off += 4L * M * I;
  f16* hq = (f16*)ws;  // overlay
  if (ws_size < off) return;

  auto kg0 = gemm256<0>;
  auto kg1 = gemm256<1>;
  hipFuncSetAttribute((const void*)kg0, hipFuncAttributeMaxDynamicSharedMemorySize, 131072);
  hipFuncSetAttribute((const void*)kg1, hipFuncAttributeMaxDynamicSharedMemorySize, 131072);

  // 1) fake-quant inputs/weights -> fp16
  {
    int g;
    g = (int)(M * H / 128);
    qdq_kernel<<<dim3((g + 3) / 4), dim3(256), 0, stream>>>(x, xq, g);
    g = (int)(I * H / 128);
    qdq_kernel<<<dim3((g + 3) / 4), dim3(256), 0, stream>>>(wg, wgq, g);
    qdq_kernel<<<dim3((g + 3) / 4), dim3(256), 0, stream>>>(wu, wuq, g);
    g = (int)(H * I / 128);
    qdq_kernel<<<dim3((g + 3) / 4), dim3(256), 0, stream>>>(wd, wdq, g);
  }

  const int NBN_I = (int)(I / 256);  // 43
  const int NBN_H = (int)(H / 256);  // 16
  const int grid_gu = (int)(M / 256) * NBN_I;  // 688 (%8==0)
  const int grid_dn = (int)(M / 256) * NBN_H;  // 256 (%8==0)

  // 2) gate = xq . wgq^T
  kg0<<<dim3(grid_gu), dim3(512), 131072, stream>>>(xq, wgq, gate, nullptr,
                                                    (int)M, (int)I, (int)H, NBN_I);
  // 3) hidden = silu(gate) * (xq . wuq^T), in-place over gate
  kg1<<<dim3(grid_gu), dim3(512), 131072, stream>>>(xq, wuq, gate, gate,
                                                    (int)M, (int)I, (int)H, NBN_I);
  // 4) fake-quant hidden -> fp16 hq (overlay)
  {
    int g = (int)(M * I / 128);
    qdq_kernel<<<dim3((g + 3) / 4), dim3(256), 0, stream>>>(gate, hq, g);
  }
  // 5) out = hq . wdq^T
  kg0<<<dim3(grid_dn), dim3(512), 131072, stream>>>(hq, wdq, out, nullptr,
                                                    (int)M, (int)H, (int)I, NBN_H);
}